// Round 9
// baseline (296.879 us; speedup 1.0000x reference)
//
#include <hip/hip_runtime.h>

// TV Chambolle, image (8, 2048, 128) f32: 29 p-updates + final out = x + div(p) + bias.
// v = b*SB + t*ST + f.
//
// R9 = R8 (RR=8, HH=4, EE=16, 2 row-groups, 512-thr blocks, (512,2), folded
// guards, edge/interior specialization) with ONE barrier per iteration:
//  - group 1 publishes its interface p row (3 comps) pre-barrier; group 0
//    computes out[GR] redundantly from LDS (no post-out exchange needed).
//  - fg==0 columns publish p0.x/p1.x/p2.x for all rows pre-barrier; fg==7
//    lanes compute the neighbor column's out.x redundantly (own P2.w is that
//    column's f-1 term; x.x at f0+4 preloaded per row).
//  - all published LDS arrays parity double-buffered (k&1): a wave cannot
//    reach publish(k+2) (same parity) before every wave passed barrier(k+1),
//    i.e. finished reading parity k. Update phase is pure register/shuffle.
// Lane map: lane = b + 8*fg; b+-1 and f+-4 via shuffles; wave-crossing f and
// group interface via the pre-barrier LDS publishes.

#define BB 8
#define TT 2048
#define FF 128
#define NV (BB*TT*FF)        // 2,097,152
#define SB (TT*FF)           // 262144
#define ST FF                // 128
#define RR 8                 // owned t-rows per block
#define NBLK (TT/RR)         // 256
#define HH 4                 // cone iterations per launch
#define EE (RR + 2*HH)       // 16 extended rows
#define GR (EE/2)            // 8 rows per row-group

constexpr float TAU = 1.0f / 6.0f;

__device__ __forceinline__ float4 ld4(const float* p) { return *reinterpret_cast<const float4*>(p); }
__device__ __forceinline__ void st4(float* p, const float4& v) { *reinterpret_cast<float4*>(p) = v; }
__device__ __forceinline__ float4 shfl_up4(float4 v, int d) {
    return make_float4(__shfl_up(v.x, d), __shfl_up(v.y, d), __shfl_up(v.z, d), __shfl_up(v.w, d));
}
__device__ __forceinline__ float4 shfl_dn4(float4 v, int d) {
    return make_float4(__shfl_down(v.x, d), __shfl_down(v.y, d), __shfl_down(v.z, d), __shfl_down(v.w, d));
}
__device__ __forceinline__ float4 sub4(const float4& a, const float4& b) {
    return make_float4(a.x - b.x, a.y - b.y, a.z - b.z, a.w - b.w);
}
__device__ __forceinline__ float4 f4z() { return make_float4(0.f, 0.f, 0.f, 0.f); }
// 1/(|g|*s + 1) elementwise; v_sqrt_f32 + v_rcp_f32 approx (12x tolerance headroom,
// sqrt(0)=0 keeps the zero-gradient corner exact).
__device__ __forceinline__ float4 nbvec(const float4& gB, const float4& gT, const float4& gF, float s) {
    float4 nb; float q;
    q = gB.x * gB.x + gT.x * gT.x + gF.x * gF.x;
    nb.x = __builtin_amdgcn_rcpf(fmaf(__builtin_amdgcn_sqrtf(q), s, 1.f));
    q = gB.y * gB.y + gT.y * gT.y + gF.y * gF.y;
    nb.y = __builtin_amdgcn_rcpf(fmaf(__builtin_amdgcn_sqrtf(q), s, 1.f));
    q = gB.z * gB.z + gT.z * gT.z + gF.z * gF.z;
    nb.z = __builtin_amdgcn_rcpf(fmaf(__builtin_amdgcn_sqrtf(q), s, 1.f));
    q = gB.w * gB.w + gT.w * gT.w + gF.w * gF.w;
    nb.w = __builtin_amdgcn_rcpf(fmaf(__builtin_amdgcn_sqrtf(q), s, 1.f));
    return nb;
}

struct ConeShared {                       // 48 KB total, parity double-buffered
    float4 pIF0[2][256];                  // group1 row-GR P0 per column
    float4 pIF1[2][256];                  // group1 row-GR P1
    float4 pIF2[2][256];                  // group1 row-GR P2
    float4 p1if[2][256];                  // group0 P1[GR-1] per column
    float  px0[2][EE][32];                // fg==0 columns' P0.x per row, col=w*8+b
    float  px1[2][EE][32];
    float  px2[2][EE][32];
    float  p2b[2][EE][32];                // fg==7 columns' P2.w per row
};

template<int RG>
__device__ __forceinline__ void publish(int par, float4 (&P0)[GR], float4 (&P1)[GR],
                                        float4 (&P2)[GR], ConeShared& sh,
                                        int c, int b, int fg, int w) {
    if (RG == 1) {
        sh.pIF0[par][c] = P0[0];
        sh.pIF1[par][c] = P1[0];
        sh.pIF2[par][c] = P2[0];
    } else {
        sh.p1if[par][c] = P1[GR - 1];
    }
    const int cw = w * 8 + b;
    if (fg == 0) {
        #pragma unroll
        for (int le = 0; le < GR; ++le) {
            const int e = RG * GR + le;
            sh.px0[par][e][cw] = P0[le].x;
            sh.px1[par][e][cw] = P1[le].x;
            sh.px2[par][e][cw] = P2[le].x;
        }
    }
    if (fg == 7) {
        #pragma unroll
        for (int le = 0; le < GR; ++le) {
            const int e = RG * GR + le;
            sh.p2b[par][e][cw] = P2[le].w;
        }
    }
}

template<int RG, bool ELO, bool EHI>
__device__ __forceinline__ void phase_out(
    int k, int par, const float4 (&Xr)[GR], const float4& XH, const float (&XH4)[GR],
    float4 (&P0)[GR], float4 (&P1)[GR], float4 (&P2)[GR], float4 (&O)[GR],
    float (&ohx)[GR], float4& OH,
    ConeShared& sh, int c, int b, int fg, int w, int f0, int tb) {
    #pragma unroll
    for (int le = 0; le < GR; ++le) {
        const int e = RG * GR + le;
        if (e < k + 1 || e >= EE - k) continue;          // compile-time row kill
        const int t = tb + e;
        if ((ELO && t < 0) || (EHI && t >= TT)) continue;
        const float4 X = Xr[le];
        float4 o;
        o.x = X.x - P0[le].x - P1[le].x - P2[le].x;
        o.y = X.y - P0[le].y - P1[le].y - P2[le].y + P2[le].x;
        o.z = X.z - P0[le].z - P1[le].z - P2[le].z + P2[le].y;
        o.w = X.w - P0[le].w - P1[le].w - P2[le].w + P2[le].z;
        float4 h0 = shfl_up4(P0[le], 1);                 // p0 at b-1
        if (b > 0) { o.x += h0.x; o.y += h0.y; o.z += h0.z; o.w += h0.w; }
        float4 pm1 = (le > 0) ? P1[le - 1] : sh.p1if[par][c];  // p1 at t-1 (LDS: RG1 le0 only)
        if (!ELO || t > 0) { o.x += pm1.x; o.y += pm1.y; o.z += pm1.z; o.w += pm1.w; }
        float pw = __shfl_up(P2[le].w, 8);               // p2.w at f0-4
        if (fg == 0) pw = (w > 0) ? sh.p2b[par][e][(w - 1) * 8 + b] : 0.0f;
        if (f0 > 0) o.x += pw;
        O[le] = o;
        // redundant out.x at the f0+4 column (next wave's fg==0 column)
        if (fg == 7 && w < 3) {
            const int cw = (w + 1) * 8 + b;
            float hx = XH4[le] - sh.px0[par][e][cw] - sh.px1[par][e][cw] - sh.px2[par][e][cw]
                     + P2[le].w;                         // p2 at (f0+4)-1 = own .w
            if (b > 0) hx += sh.px0[par][e][cw - 1];
            if (!ELO || t > 0) hx += sh.px1[par][e - 1][cw];
            ohx[le] = hx;
        }
    }
    if (RG == 0) {
        // redundant out at row GR (t = tb+GR = 8*blk+4, always in [4,2044])
        const float4 q0 = sh.pIF0[par][c];
        const float4 q1 = sh.pIF1[par][c];
        const float4 q2 = sh.pIF2[par][c];
        float4 o;
        o.x = XH.x - q0.x - q1.x - q2.x;
        o.y = XH.y - q0.y - q1.y - q2.y + q2.x;
        o.z = XH.z - q0.z - q1.z - q2.z + q2.y;
        o.w = XH.w - q0.w - q1.w - q2.w + q2.z;
        if (b > 0) {
            const float4 h = sh.pIF0[par][c - 1];        // p0 at b-1
            o.x += h.x; o.y += h.y; o.z += h.z; o.w += h.w;
        }
        o.x += P1[GR - 1].x; o.y += P1[GR - 1].y;        // p1 at t-1 = own last row
        o.z += P1[GR - 1].z; o.w += P1[GR - 1].w;
        if (f0 > 0) o.x += sh.pIF2[par][c - 8].w;        // p2.w at f0-4
        OH = o;
    }
}

template<int RG, bool ELO, bool EHI>
__device__ __forceinline__ void phase_upd(
    int k, float4 (&P0)[GR], float4 (&P1)[GR], float4 (&P2)[GR], float4 (&O)[GR],
    const float (&ohx)[GR], const float4& OH,
    int b, int fg, int w, int f0, int tb, float s) {
    #pragma unroll
    for (int le = 0; le < GR; ++le) {
        const int e = RG * GR + le;
        if (e < k + 1 || e > EE - 2 - k) continue;       // compile-time row kill
        const int t = tb + e;
        if ((ELO && t < 0) || (EHI && t >= TT)) continue;
        const float4 cc = O[le];
        const float4 on = (le < GR - 1) ? O[le + 1] : OH;   // OH reachable only for RG0
        float4 gT = f4z();
        if (!EHI || t < TT - 1) gT = sub4(on, cc);
        const float4 nB = shfl_dn4(cc, 1);               // out at b+1
        float4 gB = f4z();
        if (b < BB - 1) gB = sub4(nB, cc);
        float nxx = __shfl_down(cc.x, 8);                // out.x at f0+4
        if (fg == 7) nxx = (w < 3) ? ohx[le] : 0.0f;
        float4 gF;
        gF.x = cc.y - cc.x;
        gF.y = cc.z - cc.y;
        gF.z = cc.w - cc.z;
        gF.w = (f0 < FF - 4) ? (nxx - cc.w) : 0.f;
        const float4 nb = nbvec(gB, gT, gF, s);
        P0[le].x = fmaf(-TAU, gB.x, P0[le].x) * nb.x;
        P0[le].y = fmaf(-TAU, gB.y, P0[le].y) * nb.y;
        P0[le].z = fmaf(-TAU, gB.z, P0[le].z) * nb.z;
        P0[le].w = fmaf(-TAU, gB.w, P0[le].w) * nb.w;
        P1[le].x = fmaf(-TAU, gT.x, P1[le].x) * nb.x;
        P1[le].y = fmaf(-TAU, gT.y, P1[le].y) * nb.y;
        P1[le].z = fmaf(-TAU, gT.z, P1[le].z) * nb.z;
        P1[le].w = fmaf(-TAU, gT.w, P1[le].w) * nb.w;
        P2[le].x = fmaf(-TAU, gF.x, P2[le].x) * nb.x;
        P2[le].y = fmaf(-TAU, gF.y, P2[le].y) * nb.y;
        P2[le].z = fmaf(-TAU, gF.z, P2[le].z) * nb.z;
        P2[le].w = fmaf(-TAU, gF.w, P2[le].w) * nb.w;
    }
}

// ONE barrier per iteration; update phase is pure register/shuffle.
template<bool ELO, bool EHI>
__device__ __forceinline__ void cone_run(
    const float4 (&Xr)[GR], const float4& XH, const float (&XH4)[GR],
    float4 (&P0)[GR], float4 (&P1)[GR], float4 (&P2)[GR], float4 (&O)[GR],
    ConeShared& sh, int rg, int c, int b, int fg, int w, int f0, int tb, float s) {
    float ohx[GR];
    #pragma unroll
    for (int le = 0; le < GR; ++le) ohx[le] = 0.f;
    float4 OH = f4z();
    #pragma unroll
    for (int k = 0; k < HH; ++k) {
        const int par = k & 1;
        if (rg == 0) publish<0>(par, P0, P1, P2, sh, c, b, fg, w);
        else         publish<1>(par, P0, P1, P2, sh, c, b, fg, w);
        __syncthreads();
        if (rg == 0) {
            phase_out<0, ELO, EHI>(k, par, Xr, XH, XH4, P0, P1, P2, O, ohx, OH, sh, c, b, fg, w, f0, tb);
            phase_upd<0, ELO, EHI>(k, P0, P1, P2, O, ohx, OH, b, fg, w, f0, tb, s);
        } else {
            phase_out<1, ELO, EHI>(k, par, Xr, XH, XH4, P0, P1, P2, O, ohx, OH, sh, c, b, fg, w, f0, tb);
            phase_upd<1, ELO, EHI>(k, P0, P1, P2, O, ohx, OH, b, fg, w, f0, tb, s);
        }
    }
}

template<bool ELO, bool EHI>
__device__ __forceinline__ void tb_main(
    const float* __restrict__ x, const float* __restrict__ pin, float* __restrict__ pout,
    ConeShared& sh, int rg, int c, int b, int fg, int w, int f0, int tb, int e0,
    int base, float s) {
    float4 P0[GR], P1[GR], P2[GR], O[GR], Xr[GR];
    float  XH4[GR];
    #pragma unroll
    for (int le = 0; le < GR; ++le) {
        const int t = tb + e0 + le;
        const bool v_ok = (!ELO || t >= 0) && (!EHI || t < TT);
        if (v_ok) {
            const int v = base + t * ST;
            P0[le] = ld4(pin + v);
            P1[le] = ld4(pin + NV + v);
            P2[le] = ld4(pin + 2 * NV + v);
            Xr[le] = ld4(x + v);
        } else {
            P0[le] = f4z(); P1[le] = f4z(); P2[le] = f4z(); Xr[le] = f4z();
        }
        XH4[le] = (fg == 7 && w < 3 && v_ok) ? x[base + t * ST + 4] : 0.f;
        O[le] = f4z();
    }
    float4 XH = f4z();
    if (rg == 0) XH = ld4(x + base + (tb + GR) * ST);     // t = 8*blk+4, always valid
    cone_run<ELO, EHI>(Xr, XH, XH4, P0, P1, P2, O, sh, rg, c, b, fg, w, f0, tb, s);
    #pragma unroll
    for (int le = 0; le < GR; ++le) {
        const int e = e0 + le;
        if (e >= HH && e < HH + RR) {                     // owned rows: t always valid
            const int v = base + (tb + e) * ST;
            st4(pout + v, P0[le]);
            st4(pout + NV + v, P1[le]);
            st4(pout + 2 * NV + v, P2[le]);
        }
    }
}

__global__ __launch_bounds__(512, 2)
void k_tb(const float* __restrict__ x, const float* __restrict__ pin,
          float* __restrict__ pout, const float* __restrict__ lam) {
    __shared__ ConeShared sh;
    const int tid = threadIdx.x;
    const int blk = blockIdx.x;
    const int rg  = tid >> 8;
    const int c   = tid & 255;
    const int b   = tid & 7;
    const int fg  = (tid >> 3) & 7;
    const int w   = (tid >> 6) & 3;
    const int f0  = w * 32 + fg * 4;
    const int tb  = blk * RR - HH;
    const int e0  = rg * GR;
    const int base = b * SB + f0;
    const float s = TAU / lam[0];
    if (blk == 0 || blk == NBLK - 1)
        tb_main<true, true>(x, pin, pout, sh, rg, c, b, fg, w, f0, tb, e0, base, s);
    else
        tb_main<false, false>(x, pin, pout, sh, rg, c, b, fg, w, f0, tb, e0, base, s);
}

// First launch: iteration 1 from p==0 (out==x, barrier-free) + HH cone iters.
template<bool ELO, bool EHI>
__device__ __forceinline__ void tb_first_main(
    const float* __restrict__ x, float* __restrict__ pout,
    ConeShared& sh, int rg, int c, int b, int fg, int w, int f0, int tb, int e0,
    int base, float s) {
    float4 P0[GR], P1[GR], P2[GR], O[GR], Xr[GR], XHa;
    float  XH4[GR];
    #pragma unroll
    for (int le = 0; le < GR; ++le) {
        const int t = tb + e0 + le;
        const bool v_ok = (!ELO || t >= 0) && (!EHI || t < TT);
        Xr[le] = v_ok ? ld4(x + base + t * ST) : f4z();
        XH4[le] = (fg == 7 && w < 3 && v_ok) ? x[base + t * ST + 4] : 0.f;
        O[le] = f4z();
    }
    {
        const int t = tb + e0 + GR;                      // rg0: row GR (always valid);
        const bool v_ok = (!ELO || t >= 0) && (t < TT);  // rg1: row EE (guard t<TT even interior: max 2044 ok, but guard anyway for blk255)
        XHa = v_ok ? ld4(x + base + t * ST) : f4z();
    }
    // iteration 1: p = -TAU*grad(x) / (|grad(x)|*s + 1) on all valid rows
    #pragma unroll
    for (int le = 0; le < GR; ++le) {
        const int t = tb + e0 + le;
        if ((!ELO || t >= 0) && (!EHI || t < TT)) {
            const float4 cc = Xr[le];
            const float4 nxt = (le < GR - 1) ? Xr[le + 1] : XHa;
            float4 gT = f4z();
            if (t < TT - 1) gT = sub4(nxt, cc);
            const float4 nB = shfl_dn4(cc, 1);
            float4 gB = f4z();
            if (b < BB - 1) gB = sub4(nB, cc);
            float4 gF;
            gF.x = cc.y - cc.x;
            gF.y = cc.z - cc.y;
            gF.z = cc.w - cc.z;
            gF.w = (f0 < FF - 4) ? (x[base + t * ST + 4] - cc.w) : 0.f;
            const float4 nb = nbvec(gB, gT, gF, s);
            P0[le] = make_float4(-TAU * gB.x * nb.x, -TAU * gB.y * nb.y,
                                 -TAU * gB.z * nb.z, -TAU * gB.w * nb.w);
            P1[le] = make_float4(-TAU * gT.x * nb.x, -TAU * gT.y * nb.y,
                                 -TAU * gT.z * nb.z, -TAU * gT.w * nb.w);
            P2[le] = make_float4(-TAU * gF.x * nb.x, -TAU * gF.y * nb.y,
                                 -TAU * gF.z * nb.z, -TAU * gF.w * nb.w);
        } else {
            P0[le] = f4z(); P1[le] = f4z(); P2[le] = f4z();
        }
    }
    // for the cone, rg0 needs XH = x at row GR == XHa (e0=0). rg1's XH is unused.
    cone_run<ELO, EHI>(Xr, XHa, XH4, P0, P1, P2, O, sh, rg, c, b, fg, w, f0, tb, s);
    #pragma unroll
    for (int le = 0; le < GR; ++le) {
        const int e = e0 + le;
        if (e >= HH && e < HH + RR) {
            const int v = base + (tb + e) * ST;
            st4(pout + v, P0[le]);
            st4(pout + NV + v, P1[le]);
            st4(pout + 2 * NV + v, P2[le]);
        }
    }
}

__global__ __launch_bounds__(512, 2)
void k_tb_first(const float* __restrict__ x, float* __restrict__ pout,
                const float* __restrict__ lam) {
    __shared__ ConeShared sh;
    const int tid = threadIdx.x;
    const int blk = blockIdx.x;
    const int rg  = tid >> 8;
    const int c   = tid & 255;
    const int b   = tid & 7;
    const int fg  = (tid >> 3) & 7;
    const int w   = (tid >> 6) & 3;
    const int f0  = w * 32 + fg * 4;
    const int tb  = blk * RR - HH;
    const int e0  = rg * GR;
    const int base = b * SB + f0;
    const float s = TAU / lam[0];
    if (blk == 0 || blk == NBLK - 1)
        tb_first_main<true, true>(x, pout, sh, rg, c, b, fg, w, f0, tb, e0, base, s);
    else
        tb_first_main<false, false>(x, pout, sh, rg, c, b, fg, w, f0, tb, e0, base, s);
}

// ---- final: out = x + div(p) + bias, proven ----
__global__ __launch_bounds__(256)
void k_final(const float* __restrict__ x, const float* __restrict__ pin,
             const float* __restrict__ bias, float* __restrict__ out) {
    const int gid = blockIdx.x * 256 + threadIdx.x;
    const int v = gid * 4;
    const int f0 = v & (FF - 1);
    const int t = (v >> 7) & (TT - 1);
    const int b = v >> 18;
    const float* p0 = pin;
    const float* p1 = pin + NV;
    const float* p2 = pin + 2 * NV;
    float4 X = ld4(x + v);
    float4 a0 = ld4(p0 + v), a1 = ld4(p1 + v), a2 = ld4(p2 + v);
    float ox = X.x - a0.x - a1.x - a2.x;
    float oy = X.y - a0.y - a1.y - a2.y + a2.x;
    float oz = X.z - a0.z - a1.z - a2.z + a2.y;
    float ow = X.w - a0.w - a1.w - a2.w + a2.z;
    if (b > 0) { float4 h = ld4(p0 + v - SB); ox += h.x; oy += h.y; oz += h.z; ow += h.w; }
    if (t > 0) { float4 h = ld4(p1 + v - ST); ox += h.x; oy += h.y; oz += h.z; ow += h.w; }
    if (f0 > 0) ox += p2[v - 1];
    float4 bi = ld4(bias + f0);
    st4(out + v, make_float4(ox + bi.x, oy + bi.y, oz + bi.z, ow + bi.w));
}

extern "C" void kernel_launch(void* const* d_in, const int* in_sizes, int n_in,
                              void* d_out, int out_size, void* d_ws, size_t ws_size,
                              hipStream_t stream) {
    const float* x    = (const float*)d_in[0];
    const float* lam  = (const float*)d_in[1];
    const float* bias = (const float*)d_in[2];
    float* out = (float*)d_out;

    float* pA = (float*)d_ws;
    float* pB = pA + 3 * NV;

    // iterations 1..5 in one launch (iter-1 specialization + 4 cone iters)
    k_tb_first<<<NBLK, 512, 0, stream>>>(x, pA, lam);
    // 6 more launches x 4 iterations = 24 -> 29 total
    float* pin = pA;
    float* pout = pB;
    for (int i = 0; i < 6; ++i) {
        k_tb<<<NBLK, 512, 0, stream>>>(x, pin, pout, lam);
        float* tmp = pin; pin = pout; pout = tmp;
    }
    k_final<<<NV / 1024, 256, 0, stream>>>(x, pin, bias, out);
}

// Round 10
// 277.225 us; speedup vs baseline: 1.0709x; 1.0709x over previous
//
#include <hip/hip_runtime.h>

// TV Chambolle, image (8, 2048, 128) f32: 29 p-updates + final out = x + div(p) + bias.
// v = b*SB + t*ST + f.
//
// R10 = R8 (proven 270 us: RR=8, HH=4, 2 row-groups, 512-thr blocks, (512,2),
// folded guards, edge/interior specialization, 2 barriers/iter) with:
//  - k_final FUSED into the last temporal launch: last launch uses margin M=5
//    (EE=18, GR=9); after its 4 updates rows [4,13] are exact, so it computes
//    out = x + div(p) + bias for owned rows [5,13) in-register (one extra
//    publish+barrier reusing p2b/p1if) and stores out (8 MB) instead of p (24.5 MB).
//  - dead row-0 loads trimmed (only P1[0] of cone row 0 is ever read).
// Schedule: first(1+4) + 5 x mid(4) + last(4+out) = 29 iterations, 7 dispatches.
// R9's one-barrier redundant-halo variant REVERTED (297 us: lane-specialized
// redundant work cost more than the barrier it removed).

#define BB 8
#define TT 2048
#define FF 128
#define NV (BB*TT*FF)        // 2,097,152
#define SB (TT*FF)           // 262144
#define ST FF                // 128
#define RR 8                 // owned t-rows per block
#define NBLK (TT/RR)         // 256

constexpr float TAU = 1.0f / 6.0f;

__device__ __forceinline__ float4 ld4(const float* p) { return *reinterpret_cast<const float4*>(p); }
__device__ __forceinline__ void st4(float* p, const float4& v) { *reinterpret_cast<float4*>(p) = v; }
__device__ __forceinline__ float4 shfl_up4(float4 v, int d) {
    return make_float4(__shfl_up(v.x, d), __shfl_up(v.y, d), __shfl_up(v.z, d), __shfl_up(v.w, d));
}
__device__ __forceinline__ float4 shfl_dn4(float4 v, int d) {
    return make_float4(__shfl_down(v.x, d), __shfl_down(v.y, d), __shfl_down(v.z, d), __shfl_down(v.w, d));
}
__device__ __forceinline__ float4 sub4(const float4& a, const float4& b) {
    return make_float4(a.x - b.x, a.y - b.y, a.z - b.z, a.w - b.w);
}
__device__ __forceinline__ float4 f4z() { return make_float4(0.f, 0.f, 0.f, 0.f); }
// 1/(|g|*s + 1) elementwise; v_sqrt_f32 + v_rcp_f32 approx (12x tolerance headroom,
// sqrt(0)=0 keeps the zero-gradient corner exact).
__device__ __forceinline__ float4 nbvec(const float4& gB, const float4& gT, const float4& gF, float s) {
    float4 nb; float q;
    q = gB.x * gB.x + gT.x * gT.x + gF.x * gF.x;
    nb.x = __builtin_amdgcn_rcpf(fmaf(__builtin_amdgcn_sqrtf(q), s, 1.f));
    q = gB.y * gB.y + gT.y * gT.y + gF.y * gF.y;
    nb.y = __builtin_amdgcn_rcpf(fmaf(__builtin_amdgcn_sqrtf(q), s, 1.f));
    q = gB.z * gB.z + gT.z * gT.z + gF.z * gF.z;
    nb.z = __builtin_amdgcn_rcpf(fmaf(__builtin_amdgcn_sqrtf(q), s, 1.f));
    q = gB.w * gB.w + gT.w * gT.w + gF.w * gF.w;
    nb.w = __builtin_amdgcn_rcpf(fmaf(__builtin_amdgcn_sqrtf(q), s, 1.f));
    return nb;
}

struct ConeShared {                      // sized for max EE=18; ~12.6 KB
    float p2b[18][4][8];                 // p2.w at fg==7 per [row][w][b]
    float outx[18][4][8];                // out.x at fg==0 per [row][w][b]
    float4 p1if[256];                    // group0's P1[row GR-1] per column
    float4 oif[256];                     // group1's O[row GR]   per column
};

// ---- cone phases, templated on EE and row-group (no barriers inside) ----
template<int EEt, int RG>
__device__ __forceinline__ void publish(int k, float4 (&P1)[EEt/2], float4 (&P2)[EEt/2],
                                        ConeShared& sh, int c, int b, int fg, int w) {
    constexpr int GRt = EEt / 2;
    if (fg == 7) {
        #pragma unroll
        for (int le = 0; le < GRt; ++le) {
            const int e = RG * GRt + le;
            if (e >= k && e < EEt - k) sh.p2b[e][w][b] = P2[le].w;
        }
    }
    if (RG == 0) sh.p1if[c] = P1[GRt - 1];
}

template<int EEt, int RG, bool ELO, bool EHI>
__device__ __forceinline__ void phase_out(
    int k, const float4 (&Xr)[EEt/2],
    float4 (&P0)[EEt/2], float4 (&P1)[EEt/2], float4 (&P2)[EEt/2], float4 (&O)[EEt/2],
    ConeShared& sh, int c, int b, int fg, int w, int f0, int tb) {
    constexpr int GRt = EEt / 2;
    #pragma unroll
    for (int le = 0; le < GRt; ++le) {
        const int e = RG * GRt + le;
        if (e < k + 1 || e >= EEt - k) continue;         // compile-time row kill
        const int t = tb + e;
        if ((ELO && t < 0) || (EHI && t >= TT)) continue;
        const float4 X = Xr[le];
        float4 o;
        o.x = X.x - P0[le].x - P1[le].x - P2[le].x;
        o.y = X.y - P0[le].y - P1[le].y - P2[le].y + P2[le].x;
        o.z = X.z - P0[le].z - P1[le].z - P2[le].z + P2[le].y;
        o.w = X.w - P0[le].w - P1[le].w - P2[le].w + P2[le].z;
        float4 h0 = shfl_up4(P0[le], 1);                 // p0 at b-1
        if (b > 0) { o.x += h0.x; o.y += h0.y; o.z += h0.z; o.w += h0.w; }
        float4 pm1 = (le > 0) ? P1[le - 1] : sh.p1if[c]; // p1 at t-1 (LDS only RG1,le0)
        if (!ELO || t > 0) { o.x += pm1.x; o.y += pm1.y; o.z += pm1.z; o.w += pm1.w; }
        float pw = __shfl_up(P2[le].w, 8);               // p2.w at f0-4
        if (fg == 0) pw = (w > 0) ? sh.p2b[e][(w - 1)][b] : 0.0f;
        if (f0 > 0) o.x += pw;
        O[le] = o;
        if (fg == 0) sh.outx[e][w][b] = o.x;
    }
}

template<int EEt, int RG, bool ELO, bool EHI>
__device__ __forceinline__ void phase_upd(
    int k, float4 (&P0)[EEt/2], float4 (&P1)[EEt/2], float4 (&P2)[EEt/2], float4 (&O)[EEt/2],
    ConeShared& sh, int c, int b, int fg, int w, int f0, int tb, float s) {
    constexpr int GRt = EEt / 2;
    #pragma unroll
    for (int le = 0; le < GRt; ++le) {
        const int e = RG * GRt + le;
        if (e < k + 1 || e > EEt - 2 - k) continue;      // compile-time row kill
        const int t = tb + e;
        if ((ELO && t < 0) || (EHI && t >= TT)) continue;
        const float4 cc = O[le];
        const float4 on = (le < GRt - 1) ? O[le + 1] : sh.oif[c];  // oif only RG0,le=GRt-1
        float4 gT = f4z();
        if (!EHI || t < TT - 1) gT = sub4(on, cc);
        const float4 nB = shfl_dn4(cc, 1);               // out at b+1
        float4 gB = f4z();
        if (b < BB - 1) gB = sub4(nB, cc);
        float nxx = __shfl_down(cc.x, 8);                // out.x at f0+4
        if (fg == 7) nxx = (w < 3) ? sh.outx[e][w + 1][b] : 0.0f;
        float4 gF;
        gF.x = cc.y - cc.x;
        gF.y = cc.z - cc.y;
        gF.z = cc.w - cc.z;
        gF.w = (f0 < FF - 4) ? (nxx - cc.w) : 0.f;
        const float4 nb = nbvec(gB, gT, gF, s);
        P0[le].x = fmaf(-TAU, gB.x, P0[le].x) * nb.x;
        P0[le].y = fmaf(-TAU, gB.y, P0[le].y) * nb.y;
        P0[le].z = fmaf(-TAU, gB.z, P0[le].z) * nb.z;
        P0[le].w = fmaf(-TAU, gB.w, P0[le].w) * nb.w;
        P1[le].x = fmaf(-TAU, gT.x, P1[le].x) * nb.x;
        P1[le].y = fmaf(-TAU, gT.y, P1[le].y) * nb.y;
        P1[le].z = fmaf(-TAU, gT.z, P1[le].z) * nb.z;
        P1[le].w = fmaf(-TAU, gT.w, P1[le].w) * nb.w;
        P2[le].x = fmaf(-TAU, gF.x, P2[le].x) * nb.x;
        P2[le].y = fmaf(-TAU, gF.y, P2[le].y) * nb.y;
        P2[le].z = fmaf(-TAU, gF.z, P2[le].z) * nb.z;
        P2[le].w = fmaf(-TAU, gF.w, P2[le].w) * nb.w;
    }
}

// barriers live here, block-uniform; rg branches wrap only barrier-free compute
template<int EEt, int HHt, bool ELO, bool EHI>
__device__ __forceinline__ void cone_run(
    const float4 (&Xr)[EEt/2],
    float4 (&P0)[EEt/2], float4 (&P1)[EEt/2], float4 (&P2)[EEt/2], float4 (&O)[EEt/2],
    ConeShared& sh, int rg, int c, int b, int fg, int w, int f0, int tb, float s) {
    #pragma unroll
    for (int k = 0; k < HHt; ++k) {
        if (rg == 0) publish<EEt, 0>(k, P1, P2, sh, c, b, fg, w);
        else         publish<EEt, 1>(k, P1, P2, sh, c, b, fg, w);
        __syncthreads();
        if (rg == 0) phase_out<EEt, 0, ELO, EHI>(k, Xr, P0, P1, P2, O, sh, c, b, fg, w, f0, tb);
        else         phase_out<EEt, 1, ELO, EHI>(k, Xr, P0, P1, P2, O, sh, c, b, fg, w, f0, tb);
        if (rg == 1) sh.oif[c] = O[0];                   // out at row GRt
        __syncthreads();
        if (rg == 0) phase_upd<EEt, 0, ELO, EHI>(k, P0, P1, P2, O, sh, c, b, fg, w, f0, tb, s);
        else         phase_upd<EEt, 1, ELO, EHI>(k, P0, P1, P2, O, sh, c, b, fg, w, f0, tb, s);
    }
}

// ==================== mid launch: 4 cone iterations (EE=16, M=4) ====================
template<bool ELO, bool EHI>
__device__ __forceinline__ void mid_main(
    const float* __restrict__ x, const float* __restrict__ pin, float* __restrict__ pout,
    ConeShared& sh, int rg, int c, int b, int fg, int w, int f0, int tb, int e0,
    int base, float s) {
    constexpr int GRt = 8;
    float4 P0[GRt], P1[GRt], P2[GRt], O[GRt], Xr[GRt];
    #pragma unroll
    for (int le = 0; le < GRt; ++le) {
        const int t = tb + e0 + le;
        const bool ok = (!ELO || t >= 0) && (!EHI || t < TT);
        const bool trim = (rg == 0 && le == 0);          // row 0: only P1 ever read
        if (ok) {
            const int v = base + t * ST;
            P1[le] = ld4(pin + NV + v);
            if (!trim) {
                P0[le] = ld4(pin + v);
                P2[le] = ld4(pin + 2 * NV + v);
                Xr[le] = ld4(x + v);
            } else { P0[le] = f4z(); P2[le] = f4z(); Xr[le] = f4z(); }
        } else {
            P0[le] = f4z(); P1[le] = f4z(); P2[le] = f4z(); Xr[le] = f4z();
        }
        O[le] = f4z();
    }
    cone_run<16, 4, ELO, EHI>(Xr, P0, P1, P2, O, sh, rg, c, b, fg, w, f0, tb, s);
    #pragma unroll
    for (int le = 0; le < GRt; ++le) {
        const int e = e0 + le;
        if (e >= 4 && e < 12) {                          // owned rows: t always valid
            const int v = base + (tb + e) * ST;
            st4(pout + v, P0[le]);
            st4(pout + NV + v, P1[le]);
            st4(pout + 2 * NV + v, P2[le]);
        }
    }
}

__global__ __launch_bounds__(512, 2)
void k_mid(const float* __restrict__ x, const float* __restrict__ pin,
           float* __restrict__ pout, const float* __restrict__ lam) {
    __shared__ ConeShared sh;
    const int tid = threadIdx.x;
    const int blk = blockIdx.x;
    const int rg  = tid >> 8;
    const int c   = tid & 255;
    const int b   = tid & 7;
    const int fg  = (tid >> 3) & 7;
    const int w   = (tid >> 6) & 3;
    const int f0  = w * 32 + fg * 4;
    const int tb  = blk * RR - 4;
    const int e0  = rg * 8;
    const int base = b * SB + f0;
    const float s = TAU / lam[0];
    if (blk == 0 || blk == NBLK - 1)
        mid_main<true, true>(x, pin, pout, sh, rg, c, b, fg, w, f0, tb, e0, base, s);
    else
        mid_main<false, false>(x, pin, pout, sh, rg, c, b, fg, w, f0, tb, e0, base, s);
}

// ============ first launch: iter 1 from p==0 (out==x) + 4 cone iters (EE=16) ============
template<bool ELO, bool EHI>
__device__ __forceinline__ void first_main(
    const float* __restrict__ x, float* __restrict__ pout,
    ConeShared& sh, int rg, int c, int b, int fg, int w, int f0, int tb, int e0,
    int base, float s) {
    constexpr int GRt = 8;
    float4 P0[GRt], P1[GRt], P2[GRt], O[GRt], Xr[GRt], XHa;
    #pragma unroll
    for (int le = 0; le < GRt; ++le) {
        const int t = tb + e0 + le;
        const bool ok = (!ELO || t >= 0) && (!EHI || t < TT);
        Xr[le] = ok ? ld4(x + base + t * ST) : f4z();
        O[le] = f4z();
    }
    {
        const int t = tb + e0 + GRt;
        const bool ok = (!ELO || t >= 0) && (t < TT);
        XHa = ok ? ld4(x + base + t * ST) : f4z();
    }
    // iteration 1: p = -TAU*grad(x) / (|grad(x)|*s + 1) on all valid rows
    #pragma unroll
    for (int le = 0; le < GRt; ++le) {
        const int t = tb + e0 + le;
        if ((!ELO || t >= 0) && (!EHI || t < TT)) {
            const float4 cc = Xr[le];
            const float4 nxt = (le < GRt - 1) ? Xr[le + 1] : XHa;
            float4 gT = f4z();
            if (t < TT - 1) gT = sub4(nxt, cc);
            const float4 nB = shfl_dn4(cc, 1);
            float4 gB = f4z();
            if (b < BB - 1) gB = sub4(nB, cc);
            float4 gF;
            gF.x = cc.y - cc.x;
            gF.y = cc.z - cc.y;
            gF.z = cc.w - cc.z;
            gF.w = (f0 < FF - 4) ? (x[base + t * ST + 4] - cc.w) : 0.f;
            const float4 nb = nbvec(gB, gT, gF, s);
            P0[le] = make_float4(-TAU * gB.x * nb.x, -TAU * gB.y * nb.y,
                                 -TAU * gB.z * nb.z, -TAU * gB.w * nb.w);
            P1[le] = make_float4(-TAU * gT.x * nb.x, -TAU * gT.y * nb.y,
                                 -TAU * gT.z * nb.z, -TAU * gT.w * nb.w);
            P2[le] = make_float4(-TAU * gF.x * nb.x, -TAU * gF.y * nb.y,
                                 -TAU * gF.z * nb.z, -TAU * gF.w * nb.w);
        } else {
            P0[le] = f4z(); P1[le] = f4z(); P2[le] = f4z();
        }
    }
    cone_run<16, 4, ELO, EHI>(Xr, P0, P1, P2, O, sh, rg, c, b, fg, w, f0, tb, s);
    #pragma unroll
    for (int le = 0; le < GRt; ++le) {
        const int e = e0 + le;
        if (e >= 4 && e < 12) {
            const int v = base + (tb + e) * ST;
            st4(pout + v, P0[le]);
            st4(pout + NV + v, P1[le]);
            st4(pout + 2 * NV + v, P2[le]);
        }
    }
}

__global__ __launch_bounds__(512, 2)
void k_first(const float* __restrict__ x, float* __restrict__ pout,
             const float* __restrict__ lam) {
    __shared__ ConeShared sh;
    const int tid = threadIdx.x;
    const int blk = blockIdx.x;
    const int rg  = tid >> 8;
    const int c   = tid & 255;
    const int b   = tid & 7;
    const int fg  = (tid >> 3) & 7;
    const int w   = (tid >> 6) & 3;
    const int f0  = w * 32 + fg * 4;
    const int tb  = blk * RR - 4;
    const int e0  = rg * 8;
    const int base = b * SB + f0;
    const float s = TAU / lam[0];
    if (blk == 0 || blk == NBLK - 1)
        first_main<true, true>(x, pout, sh, rg, c, b, fg, w, f0, tb, e0, base, s);
    else
        first_main<false, false>(x, pout, sh, rg, c, b, fg, w, f0, tb, e0, base, s);
}

// ======== last launch: 4 cone iters (EE=18, M=5) + fused out = x + div(p) + bias ========
template<bool ELO, bool EHI>
__device__ __forceinline__ void last_main(
    const float* __restrict__ x, const float* __restrict__ pin,
    const float* __restrict__ bias, float* __restrict__ out,
    ConeShared& sh, int rg, int c, int b, int fg, int w, int f0, int tb, int e0,
    int base, float s) {
    constexpr int GRt = 9;
    float4 P0[GRt], P1[GRt], P2[GRt], O[GRt], Xr[GRt];
    #pragma unroll
    for (int le = 0; le < GRt; ++le) {
        const int t = tb + e0 + le;
        const bool ok = (!ELO || t >= 0) && (!EHI || t < TT);
        const bool trim = (rg == 0 && le == 0);
        if (ok) {
            const int v = base + t * ST;
            P1[le] = ld4(pin + NV + v);
            if (!trim) {
                P0[le] = ld4(pin + v);
                P2[le] = ld4(pin + 2 * NV + v);
                Xr[le] = ld4(x + v);
            } else { P0[le] = f4z(); P2[le] = f4z(); Xr[le] = f4z(); }
        } else {
            P0[le] = f4z(); P1[le] = f4z(); P2[le] = f4z(); Xr[le] = f4z();
        }
        O[le] = f4z();
    }
    cone_run<18, 4, ELO, EHI>(Xr, P0, P1, P2, O, sh, rg, c, b, fg, w, f0, tb, s);
    // after 4 updates: rows [4,13] exact. Epilogue out rows [5,13).
    if (rg == 0) publish<18, 0>(4, P1, P2, sh, c, b, fg, w);   // k=4 guard covers [4,14)
    else         publish<18, 1>(4, P1, P2, sh, c, b, fg, w);
    __syncthreads();
    const float4 bi = ld4(bias + f0);
    #pragma unroll
    for (int le = 0; le < GRt; ++le) {
        const int e = e0 + le;
        if (e < 5 || e >= 13) continue;                  // epilogue rows only
        const int t = tb + e;                            // always in [0, TT)
        const float4 X = Xr[le];
        float4 o;
        o.x = X.x - P0[le].x - P1[le].x - P2[le].x;
        o.y = X.y - P0[le].y - P1[le].y - P2[le].y + P2[le].x;
        o.z = X.z - P0[le].z - P1[le].z - P2[le].z + P2[le].y;
        o.w = X.w - P0[le].w - P1[le].w - P2[le].w + P2[le].z;
        float4 h0 = shfl_up4(P0[le], 1);                 // p0 at b-1
        if (b > 0) { o.x += h0.x; o.y += h0.y; o.z += h0.z; o.w += h0.w; }
        float4 pm1 = (le > 0) ? P1[le - 1] : sh.p1if[c]; // p1 at t-1 (LDS: rg1,le0)
        if (!ELO || t > 0) { o.x += pm1.x; o.y += pm1.y; o.z += pm1.z; o.w += pm1.w; }
        float pw = __shfl_up(P2[le].w, 8);               // p2.w at f0-4
        if (fg == 0) pw = (w > 0) ? sh.p2b[e][w - 1][b] : 0.0f;
        if (f0 > 0) o.x += pw;
        o.x += bi.x; o.y += bi.y; o.z += bi.z; o.w += bi.w;
        st4(out + base + t * ST, o);
    }
}

__global__ __launch_bounds__(512, 2)
void k_last(const float* __restrict__ x, const float* __restrict__ pin,
            const float* __restrict__ bias, float* __restrict__ out,
            const float* __restrict__ lam) {
    __shared__ ConeShared sh;
    const int tid = threadIdx.x;
    const int blk = blockIdx.x;
    const int rg  = tid >> 8;
    const int c   = tid & 255;
    const int b   = tid & 7;
    const int fg  = (tid >> 3) & 7;
    const int w   = (tid >> 6) & 3;
    const int f0  = w * 32 + fg * 4;
    const int tb  = blk * RR - 5;                        // margin M=5
    const int e0  = rg * 9;
    const int base = b * SB + f0;
    const float s = TAU / lam[0];
    if (blk == 0 || blk == NBLK - 1)
        last_main<true, true>(x, pin, bias, out, sh, rg, c, b, fg, w, f0, tb, e0, base, s);
    else
        last_main<false, false>(x, pin, bias, out, sh, rg, c, b, fg, w, f0, tb, e0, base, s);
}

extern "C" void kernel_launch(void* const* d_in, const int* in_sizes, int n_in,
                              void* d_out, int out_size, void* d_ws, size_t ws_size,
                              hipStream_t stream) {
    const float* x    = (const float*)d_in[0];
    const float* lam  = (const float*)d_in[1];
    const float* bias = (const float*)d_in[2];
    float* out = (float*)d_out;

    float* pA = (float*)d_ws;
    float* pB = pA + 3 * NV;

    // iterations 1..5 (iter-1 specialization + 4 cone iters)
    k_first<<<NBLK, 512, 0, stream>>>(x, pA, lam);
    // iterations 6..25: 5 launches x 4
    float* pin = pA;
    float* pout = pB;
    for (int i = 0; i < 5; ++i) {
        k_mid<<<NBLK, 512, 0, stream>>>(x, pin, pout, lam);
        float* tmp = pin; pin = pout; pout = tmp;
    }
    // iterations 26..29 + fused out = x + div(p) + bias
    k_last<<<NBLK, 512, 0, stream>>>(x, pin, bias, out, lam);
}